// Round 1
// baseline (24.459 us; speedup 1.0000x reference)
//
#include <hip/hip_runtime.h>
#include <hip/hip_bf16.h>

// Problem: B=64, Cin=64, Cout=128, H=W=64, K=3.
// ConvTranspose2d(stride=1,pad=0) -> spatial mean factorizes:
//   gap[b,o] = (1/4356) * sum_i Sx[b,i] * Sw[i,o] + bias[o]
//   out[b]   = 10 * logsumexp_o(gap[b,o])
// where Sx[b,i] = sum_{h,w} x[b,i,h,w], Sw[i,o] = sum_{kh,kw} w[i,o,kh,kw].

#define HW 4096          // 64*64 spatial elements per (b,i) row
#define CIN 64
#define COUT 128
#define BATCH 64
#define INV_AREA (1.0f / 4356.0f)   // 1/(66*66)

// ---------------- Kernel 1: spatial sums of x --------------------------
// One block per (b*Cin + i) row of 4096 floats. 256 threads, 4x float4 each.
__global__ __launch_bounds__(256) void spatial_sum_kernel(
    const float* __restrict__ x, float* __restrict__ sx)
{
    const int row = blockIdx.x;                  // 0 .. 4095
    const float4* p = reinterpret_cast<const float4*>(x) + (size_t)row * (HW / 4);
    const int t = threadIdx.x;

    float s = 0.0f;
#pragma unroll
    for (int k = 0; k < 4; ++k) {
        float4 v = p[t + k * 256];
        s += (v.x + v.y) + (v.z + v.w);
    }
    // intra-wave (64-lane) butterfly reduce
#pragma unroll
    for (int off = 32; off > 0; off >>= 1)
        s += __shfl_xor(s, off, 64);

    __shared__ float wsum[4];
    const int wid  = t >> 6;
    const int lane = t & 63;
    if (lane == 0) wsum[wid] = s;
    __syncthreads();
    if (t == 0)
        sx[row] = (wsum[0] + wsum[1]) + (wsum[2] + wsum[3]);
}

// ---------------- Kernel 2: gap + logsumexp epilogue -------------------
// One block per batch b; 128 threads = one per output channel o.
__global__ __launch_bounds__(128) void gap_lse_kernel(
    const float* __restrict__ sx,      // (B, Cin)
    const float* __restrict__ weight,  // (Cin, Cout, 3, 3)
    const float* __restrict__ bias,    // (Cout)
    float* __restrict__ out)           // (B)
{
    const int b = blockIdx.x;
    const int o = threadIdx.x;         // 0 .. 127

    __shared__ float sxs[CIN];
    if (o < CIN) sxs[o] = sx[b * CIN + o];
    __syncthreads();

    // dot over input channels; Sw computed inline (weight is L2-resident)
    float acc = 0.0f;
#pragma unroll 4
    for (int i = 0; i < CIN; ++i) {
        const float* wp = weight + ((size_t)i * COUT + o) * 9;
        float sw = 0.0f;
#pragma unroll
        for (int k = 0; k < 9; ++k) sw += wp[k];
        acc = fmaf(sxs[i], sw, acc);
    }
    const float gap = fmaf(acc, INV_AREA, bias[o]);

    // logsumexp across 128 threads (2 waves)
    float m = gap;
#pragma unroll
    for (int off = 32; off > 0; off >>= 1)
        m = fmaxf(m, __shfl_xor(m, off, 64));

    __shared__ float wmax[2], wacc[2];
    const int wid = o >> 6;
    if ((o & 63) == 0) wmax[wid] = m;
    __syncthreads();
    const float M = fmaxf(wmax[0], wmax[1]);

    float e = __expf(gap - M);
#pragma unroll
    for (int off = 32; off > 0; off >>= 1)
        e += __shfl_xor(e, off, 64);
    if ((o & 63) == 0) wacc[wid] = e;
    __syncthreads();

    if (o == 0)
        out[b] = 10.0f * (logf(wacc[0] + wacc[1]) + M);
}

extern "C" void kernel_launch(void* const* d_in, const int* in_sizes, int n_in,
                              void* d_out, int out_size, void* d_ws, size_t ws_size,
                              hipStream_t stream) {
    const float* x      = (const float*)d_in[0];  // (64,64,64,64)
    const float* weight = (const float*)d_in[1];  // (64,128,3,3)
    const float* bias   = (const float*)d_in[2];  // (128,1,1)
    float* out = (float*)d_out;                   // (64,1) -> 64 floats
    float* sx  = (float*)d_ws;                    // (64,64) scratch

    spatial_sum_kernel<<<BATCH * CIN, 256, 0, stream>>>(x, sx);
    gap_lse_kernel<<<BATCH, 128, 0, stream>>>(sx, weight, bias, out);
}

// Round 3
// 16.030 us; speedup vs baseline: 1.5258x; 1.5258x over previous
//
#include <hip/hip_runtime.h>
#include <hip/hip_bf16.h>

// Problem: B=64, Cin=64, Cout=128, H=W=64, K=3.
// ConvTranspose2d(stride=1,pad=0) -> spatial mean factorizes:
//   gap[b,o] = (1/4356) * sum_i Sx[b,i] * Sw[i,o] + bias[o]
//   out[b]   = 10 * logsumexp_o(gap[b,o])
// where Sx[b,i] = sum_{h,w} x[b,i,h,w], Sw[i,o] = sum_{kh,kw} w[i,o,kh,kw].

#define HW 4096          // 64*64 spatial elements per (b,i) row
#define CIN 64
#define COUT 128
#define BATCH 64
#define INV_AREA (1.0f / 4356.0f)   // 1/(66*66)

typedef float f4 __attribute__((ext_vector_type(4)));  // clang vector: OK for nontemporal builtin

// ---------------- Kernel 1: spatial sums of x + Sw side-duty -----------
// One block per (b*Cin + i) row of 4096 floats. 256 threads, 4x float4 each.
// Blocks 0..15 additionally compute one 256-wide chunk of Sw (i*128+o).
__global__ __launch_bounds__(256) void spatial_sum_kernel(
    const float* __restrict__ x, const float* __restrict__ weight,
    float* __restrict__ sx, float* __restrict__ sws)
{
    const int row = blockIdx.x;                  // 0 .. 4095
    const int t = threadIdx.x;

    // Side duty: Sw[p] for p = i*128+o, 16 blocks x 256 threads = 4096 pairs.
    // Issued first so the 9 scalar loads overlap the x-stream below.
    if (row < (CIN * COUT) / 256) {
        const int p = row * 256 + t;
        const float* wp = weight + (size_t)p * 9;
        float sw = 0.0f;
#pragma unroll
        for (int k = 0; k < 9; ++k) sw += wp[k];
        sws[p] = sw;
    }

    const f4* p4 = reinterpret_cast<const f4*>(x) + (size_t)row * (HW / 4);
    float s = 0.0f;
#pragma unroll
    for (int k = 0; k < 4; ++k) {
        f4 v = __builtin_nontemporal_load(&p4[t + k * 256]);
        s += (v.x + v.y) + (v.z + v.w);
    }
    // intra-wave (64-lane) butterfly reduce
#pragma unroll
    for (int off = 32; off > 0; off >>= 1)
        s += __shfl_xor(s, off, 64);

    __shared__ float wsum[4];
    const int wid  = t >> 6;
    const int lane = t & 63;
    if (lane == 0) wsum[wid] = s;
    __syncthreads();
    if (t == 0)
        sx[row] = (wsum[0] + wsum[1]) + (wsum[2] + wsum[3]);
}

// ---------------- Kernel 2: gap + logsumexp epilogue -------------------
// One block per batch b; 128 threads = one per output channel o.
__global__ __launch_bounds__(128) void gap_lse_kernel(
    const float* __restrict__ sx,      // (B, Cin)
    const float* __restrict__ sws,     // (Cin, Cout) pre-summed kernel taps
    const float* __restrict__ bias,    // (Cout)
    float* __restrict__ out)           // (B)
{
    const int b = blockIdx.x;
    const int o = threadIdx.x;         // 0 .. 127

    __shared__ float sxs[CIN];
    if (o < CIN) sxs[o] = sx[b * CIN + o];
    __syncthreads();

    // 64 independent coalesced L2-hit loads, fully unrolled.
    float acc = 0.0f;
#pragma unroll
    for (int i = 0; i < CIN; ++i)
        acc = fmaf(sxs[i], sws[i * COUT + o], acc);
    const float gap = fmaf(acc, INV_AREA, bias[o]);

    // logsumexp across 128 threads (2 waves)
    float m = gap;
#pragma unroll
    for (int off = 32; off > 0; off >>= 1)
        m = fmaxf(m, __shfl_xor(m, off, 64));

    __shared__ float wmax[2], wacc[2];
    const int wid = o >> 6;
    if ((o & 63) == 0) wmax[wid] = m;
    __syncthreads();
    const float M = fmaxf(wmax[0], wmax[1]);

    float e = __expf(gap - M);
#pragma unroll
    for (int off = 32; off > 0; off >>= 1)
        e += __shfl_xor(e, off, 64);
    if ((o & 63) == 0) wacc[wid] = e;
    __syncthreads();

    if (o == 0)
        out[b] = 10.0f * (logf(wacc[0] + wacc[1]) + M);
}

extern "C" void kernel_launch(void* const* d_in, const int* in_sizes, int n_in,
                              void* d_out, int out_size, void* d_ws, size_t ws_size,
                              hipStream_t stream) {
    const float* x      = (const float*)d_in[0];  // (64,64,64,64)
    const float* weight = (const float*)d_in[1];  // (64,128,3,3)
    const float* bias   = (const float*)d_in[2];  // (128,1,1)
    float* out = (float*)d_out;                   // (64,1) -> 64 floats
    float* sx  = (float*)d_ws;                    // (64,64) scratch
    float* sws = (float*)d_ws + BATCH * CIN;      // (64,128) scratch

    spatial_sum_kernel<<<BATCH * CIN, 256, 0, stream>>>(x, weight, sx, sws);
    gap_lse_kernel<<<BATCH, 128, 0, stream>>>(sx, sws, bias, out);
}